// Round 3
// baseline (144.806 us; speedup 1.0000x reference)
//
#include <hip/hip_runtime.h>
#include <math.h>

#define IN_F   1024
#define OUT_F  1024
#define TASK_D 256
#define RANK   8
#define HID    64
// SCALING = ALPHA / RANK = 1.0 (identity)

__device__ __forceinline__ float gelu_exact(float v) {
    return 0.5f * v * (1.0f + erff(v * 0.70710678118654752f));
}

// ---------------------------------------------------------------------------
// Kernel 1: generate LoRA tables for all 4 tasks.
//   vec_a_t : [4][RANK][OUT_F]  (TRANSPOSED: a_t[t][r][o] = a[t][o][r])
//   vec_b   : [4][RANK][IN_F]
// ---------------------------------------------------------------------------
__global__ __launch_bounds__(256) void gen_kernel(
    const float* __restrict__ task_emb,
    const float* __restrict__ Wa1, const float* __restrict__ ba1,
    const float* __restrict__ Wa2, const float* __restrict__ ba2,
    const float* __restrict__ Wb1, const float* __restrict__ bb1,
    const float* __restrict__ Wb2, const float* __restrict__ bb2,
    float* __restrict__ vec_a_t, float* __restrict__ vec_b)
{
    const int gen = blockIdx.x >> 7;             // 0 -> a, 1 -> b
    const int blk = blockIdx.x & 127;
    const float* __restrict__ W1 = gen ? Wb1 : Wa1;
    const float* __restrict__ b1 = gen ? bb1 : ba1;
    const float* __restrict__ W2 = gen ? Wb2 : Wa2;
    const float* __restrict__ b2 = gen ? bb2 : ba2;

    __shared__ float hs[4][HID];
    {
        const int j = threadIdx.x >> 2;          // hidden unit 0..63
        const int t = threadIdx.x & 3;           // task 0..3
        const float4* te = (const float4*)(task_emb + t * TASK_D);
        const float4* w  = (const float4*)(W1 + j * TASK_D);
        float acc = 0.f;
        #pragma unroll
        for (int d = 0; d < TASK_D / 4; ++d) {
            float4 a = te[d], b = w[d];
            acc += a.x * b.x + a.y * b.y + a.z * b.z + a.w * b.w;
        }
        hs[t][j] = gelu_exact(acc + b1[j]);
    }
    __syncthreads();

    const int lrow = threadIdx.x >> 2;           // 0..63  (W2 row within block)
    const int q    = threadIdx.x & 3;            // quarter of the 64 hidden dims
    const int o    = blk * 64 + lrow;            // W2 row 0..8191

    const float4* w2 = (const float4*)(W2 + (size_t)o * HID + q * 16);
    float acc0 = 0.f, acc1 = 0.f, acc2 = 0.f, acc3 = 0.f;
    #pragma unroll
    for (int k = 0; k < 4; ++k) {
        float4 w = w2[k];
        const int kb = q * 16 + k * 4;
        acc0 += hs[0][kb] * w.x + hs[0][kb+1] * w.y + hs[0][kb+2] * w.z + hs[0][kb+3] * w.w;
        acc1 += hs[1][kb] * w.x + hs[1][kb+1] * w.y + hs[1][kb+2] * w.z + hs[1][kb+3] * w.w;
        acc2 += hs[2][kb] * w.x + hs[2][kb+1] * w.y + hs[2][kb+2] * w.z + hs[2][kb+3] * w.w;
        acc3 += hs[3][kb] * w.x + hs[3][kb+1] * w.y + hs[3][kb+2] * w.z + hs[3][kb+3] * w.w;
    }
    #pragma unroll
    for (int off = 1; off <= 2; off <<= 1) {
        acc0 += __shfl_xor(acc0, off, 64);
        acc1 += __shfl_xor(acc1, off, 64);
        acc2 += __shfl_xor(acc2, off, 64);
        acc3 += __shfl_xor(acc3, off, 64);
    }
    if (q == 0) {
        const float bb = b2[o];
        float v[4] = { acc0 + bb, acc1 + bb, acc2 + bb, acc3 + bb };
        if (gen == 0) {
            const int oo = o >> 3, r = o & 7;    // vec_a row o -> (out oo, rank r)
            #pragma unroll
            for (int t = 0; t < 4; ++t)
                vec_a_t[t * (RANK * OUT_F) + r * OUT_F + oo] = v[t];
        } else {
            #pragma unroll
            for (int t = 0; t < 4; ++t)
                vec_b[t * (RANK * IN_F) + o] = v[t];
        }
    }
}

// ---------------------------------------------------------------------------
// Kernel 2: fused LoRA apply, latency-pipelined.
// 1024 blocks x 256 threads, one task per block, vec_b[t] in LDS (32 KB),
// 2 rows per wave. Key ordering:
//   - all 8 x float4 loads issued BEFORE the staging __syncthreads()
//     (global latency overlaps the LDS fill + barrier)
//   - phase 1 is chunk-outer: each bv (ds_read_b128) is shared by both rows
//   - epilogue: all 8 base_out float4 loads batched up front; a-frags
//     shared across both rows
// ---------------------------------------------------------------------------
__global__ __launch_bounds__(256) void apply_kernel(
    const float* __restrict__ x, const float* __restrict__ base_out,
    const float* __restrict__ vec_a_t, const float* __restrict__ vec_b,
    float* __restrict__ out)
{
    const int t    = blockIdx.x & 3;             // task
    const int g    = blockIdx.x >> 2;            // group within task
    const int wave = threadIdx.x >> 6;
    const int lane = threadIdx.x & 63;

    __shared__ float bs[RANK * IN_F];            // 32 KB
    {
        const float4* src = (const float4*)(vec_b + (size_t)t * (RANK * IN_F));
        float4* dst = (float4*)bs;
        #pragma unroll
        for (int i = 0; i < 8; ++i)
            dst[threadIdx.x + 256 * i] = src[threadIdx.x + 256 * i];
    }

    const int jbase = g * 8 + wave * 2;          // row / 4
    const int row0  = t + 4 * jbase;
    const int row1  = row0 + 4;

    // Issue all x loads before the barrier: HBM latency overlaps staging.
    float4 xv[2][4];
    {
        const float* __restrict__ xr0 = x + (size_t)row0 * IN_F;
        const float* __restrict__ xr1 = x + (size_t)row1 * IN_F;
        #pragma unroll
        for (int c = 0; c < 4; ++c) {
            xv[0][c] = *(const float4*)(xr0 + c * 256 + lane * 4);
            xv[1][c] = *(const float4*)(xr1 + c * 256 + lane * 4);
        }
    }

    __syncthreads();

    // Phase 1: chunk-outer rank dots; bv shared across both rows.
    float acc[2][RANK];
    #pragma unroll
    for (int i = 0; i < 2; ++i)
        #pragma unroll
        for (int r = 0; r < RANK; ++r) acc[i][r] = 0.f;

    #pragma unroll
    for (int c = 0; c < 4; ++c) {
        const int k = c * 256 + lane * 4;
        #pragma unroll
        for (int r = 0; r < RANK; ++r) {
            const float4 bv = *(const float4*)(bs + r * IN_F + k);
            acc[0][r] += xv[0][c].x * bv.x + xv[0][c].y * bv.y
                       + xv[0][c].z * bv.z + xv[0][c].w * bv.w;
            acc[1][r] += xv[1][c].x * bv.x + xv[1][c].y * bv.y
                       + xv[1][c].z * bv.z + xv[1][c].w * bv.w;
        }
    }

    // Butterfly reduce all 16 accumulators across the wave.
    #pragma unroll
    for (int off = 32; off > 0; off >>= 1) {
        #pragma unroll
        for (int i = 0; i < 2; ++i)
            #pragma unroll
            for (int r = 0; r < RANK; ++r)
                acc[i][r] += __shfl_xor(acc[i][r], off, 64);
    }

    // Epilogue: batch base_out loads, then stream a-frags (L1/L2) + FMA.
    const float* __restrict__ at = vec_a_t + (size_t)t * (RANK * OUT_F);
    const float* __restrict__ br0 = base_out + (size_t)row0 * OUT_F;
    const float* __restrict__ br1 = base_out + (size_t)row1 * OUT_F;
    float*       __restrict__ or0 = out + (size_t)row0 * OUT_F;
    float*       __restrict__ or1 = out + (size_t)row1 * OUT_F;

    float4 bo[2][4];
    #pragma unroll
    for (int c = 0; c < 4; ++c) {
        const int o = c * 256 + lane * 4;
        bo[0][c] = *(const float4*)(br0 + o);
        bo[1][c] = *(const float4*)(br1 + o);
    }

    #pragma unroll
    for (int c = 0; c < 4; ++c) {
        const int o = c * 256 + lane * 4;
        float4 rv0 = bo[0][c];
        float4 rv1 = bo[1][c];
        #pragma unroll
        for (int r = 0; r < RANK; ++r) {
            const float4 af = *(const float4*)(at + r * OUT_F + o);
            rv0.x += acc[0][r] * af.x;  rv0.y += acc[0][r] * af.y;
            rv0.z += acc[0][r] * af.z;  rv0.w += acc[0][r] * af.w;
            rv1.x += acc[1][r] * af.x;  rv1.y += acc[1][r] * af.y;
            rv1.z += acc[1][r] * af.z;  rv1.w += acc[1][r] * af.w;
        }
        *(float4*)(or0 + o) = rv0;
        *(float4*)(or1 + o) = rv1;
    }
}

extern "C" void kernel_launch(void* const* d_in, const int* in_sizes, int n_in,
                              void* d_out, int out_size, void* d_ws, size_t ws_size,
                              hipStream_t stream) {
    const float* x        = (const float*)d_in[0];
    const float* base_out = (const float*)d_in[1];
    const float* task_emb = (const float*)d_in[2];
    const float* Wa1      = (const float*)d_in[3];
    const float* ba1      = (const float*)d_in[4];
    const float* Wa2      = (const float*)d_in[5];
    const float* ba2      = (const float*)d_in[6];
    const float* Wb1      = (const float*)d_in[7];
    const float* bb1      = (const float*)d_in[8];
    const float* Wb2      = (const float*)d_in[9];
    const float* bb2      = (const float*)d_in[10];
    float* out = (float*)d_out;

    float* vec_a_t = (float*)d_ws;                        // 4*8192 floats
    float* vec_b   = vec_a_t + 4 * RANK * OUT_F;          // 4*8192 floats

    const int b_eff = in_sizes[0] / IN_F;                 // 8192

    gen_kernel<<<256, 256, 0, stream>>>(task_emb, Wa1, ba1, Wa2, ba2,
                                        Wb1, bb1, Wb2, bb2, vec_a_t, vec_b);
    apply_kernel<<<b_eff / 8, 256, 0, stream>>>(x, base_out, vec_a_t, vec_b, out);
}